// Round 1
// baseline (287.563 us; speedup 1.0000x reference)
//
#include <hip/hip_runtime.h>

typedef __attribute__((ext_vector_type(8))) __bf16 bf16x8;
typedef __attribute__((ext_vector_type(4))) float f32x4;
typedef __attribute__((ext_vector_type(8))) unsigned short ushort8;

#define DSAMP 512
#define DIM   128
#define ROWB  144   // LDS row pitch in bytes: 64 bf16 = 128 B + 16 B pad

// Block tile: 128x128 of one distance matrix. 256 threads = 4 waves,
// each wave owns a 64x64 quadrant as 4x4 MFMA tiles (16x16x32 bf16).
// fp32 inputs are split on the fly into bf16 hi/lo; dot = hh + hl + lh.
__global__ __launch_bounds__(256, 2)
void mmd_tile_kernel(const float* __restrict__ x, const float* __restrict__ y,
                     float* __restrict__ partials) {
    __shared__ __align__(16) char smem[4 * 128 * ROWB];   // Ah, Al, Bh, Bl
    __shared__ float Pn[128];
    __shared__ float Qn[128];
    __shared__ float wred[4];

    char* Ah = smem;
    char* Al = smem + 1 * 128 * ROWB;
    char* Bh = smem + 2 * 128 * ROWB;
    char* Bl = smem + 3 * 128 * ROWB;

    const int tid  = threadIdx.x;
    const int bid  = blockIdx.x;
    const int tj   = bid & 3;
    const int ti   = (bid >> 2) & 3;
    const int type = (bid >> 4) % 3;   // 0: xy, 1: xx, 2: yy
    const int b    = bid / 48;

    const float* Xb = x + (size_t)b * DSAMP * DIM;
    const float* Yb = y + (size_t)b * DSAMP * DIM;
    const float* Pp; const float* Qp; float w;
    if (type == 0)      { Pp = Xb; Qp = Yb; w = 1.0f;  }
    else if (type == 1) { Pp = Xb; Qp = Xb; w = -0.5f; }
    else                { Pp = Yb; Qp = Yb; w = -0.5f; }
    Pp += (size_t)ti * 128 * DIM;
    Qp += (size_t)tj * 128 * DIM;

    // ---- row norms (fp32, full K) ----
    {
        const float* rp = (tid < 128) ? (Pp + (size_t)tid * DIM)
                                      : (Qp + (size_t)(tid - 128) * DIM);
        float s = 0.f;
        #pragma unroll
        for (int k4 = 0; k4 < 32; ++k4) {
            float4 v = ((const float4*)rp)[k4];
            s += v.x * v.x + v.y * v.y + v.z * v.z + v.w * v.w;
        }
        if (tid < 128) Pn[tid] = s; else Qn[tid - 128] = s;
    }

    const int lane    = tid & 63;
    const int wv      = tid >> 6;
    const int rowHalf = (wv >> 1) * 64;
    const int colHalf = (wv & 1) * 64;
    const int fm      = lane & 15;   // frag row / C col
    const int kq      = lane >> 4;   // k-quad / C row group

    f32x4 acc[4][4];
    #pragma unroll
    for (int a2 = 0; a2 < 4; ++a2)
        #pragma unroll
        for (int b2 = 0; b2 < 4; ++b2)
            acc[a2][b2] = (f32x4){0.f, 0.f, 0.f, 0.f};

    // ---- K loop: 2 chunks of 64 ----
    for (int c = 0; c < 2; ++c) {
        if (c) __syncthreads();   // previous chunk's compute done before overwrite
        // stage: fp32 -> bf16 hi/lo -> LDS (8 floats / unit -> one b128 per array)
        #pragma unroll
        for (int side = 0; side < 2; ++side) {
            const float* sp = side ? Qp : Pp;
            char* dh = side ? Bh : Ah;
            char* dl = side ? Bl : Al;
            #pragma unroll
            for (int it = 0; it < 4; ++it) {
                int u  = it * 256 + tid;       // 0..1023
                int r  = u >> 3;               // row 0..127
                int c8 = u & 7;                // float8 chunk within 64-k slice
                const float* g = sp + (size_t)r * DIM + c * 64 + c8 * 8;
                float4 v0 = ((const float4*)g)[0];
                float4 v1 = ((const float4*)g)[1];
                float xs[8] = {v0.x, v0.y, v0.z, v0.w, v1.x, v1.y, v1.z, v1.w};
                ushort8 hv, lv;
                #pragma unroll
                for (int e = 0; e < 8; ++e) {
                    float xv = xs[e];
                    unsigned ub = __float_as_uint(xv);
                    unsigned hr = (ub + 0x7fffu + ((ub >> 16) & 1u)) >> 16;
                    float hf = __uint_as_float(hr << 16);
                    float rs = xv - hf;                       // exact (Dekker split)
                    unsigned ul = __float_as_uint(rs);
                    unsigned lr = (ul + 0x7fffu + ((ul >> 16) & 1u)) >> 16;
                    hv[e] = (unsigned short)hr;
                    lv[e] = (unsigned short)lr;
                }
                *(ushort8*)(dh + r * ROWB + c8 * 16) = hv;
                *(ushort8*)(dl + r * ROWB + c8 * 16) = lv;
            }
        }
        __syncthreads();
        // compute: 2 k-steps of 32
        #pragma unroll
        for (int ks = 0; ks < 2; ++ks) {
            const int kb2 = (ks * 32 + kq * 8) * 2;   // byte offset into row
            bf16x8 ah[4], al[4], bh[4], bl[4];
            #pragma unroll
            for (int a2 = 0; a2 < 4; ++a2) {
                int ar = rowHalf + a2 * 16 + fm;
                ah[a2] = *(const bf16x8*)(Ah + ar * ROWB + kb2);
                al[a2] = *(const bf16x8*)(Al + ar * ROWB + kb2);
            }
            #pragma unroll
            for (int b2 = 0; b2 < 4; ++b2) {
                int br = colHalf + b2 * 16 + fm;
                bh[b2] = *(const bf16x8*)(Bh + br * ROWB + kb2);
                bl[b2] = *(const bf16x8*)(Bl + br * ROWB + kb2);
            }
            #pragma unroll
            for (int a2 = 0; a2 < 4; ++a2)
                #pragma unroll
                for (int b2 = 0; b2 < 4; ++b2) {
                    acc[a2][b2] = __builtin_amdgcn_mfma_f32_16x16x32_bf16(ah[a2], bh[b2], acc[a2][b2], 0, 0, 0);
                    acc[a2][b2] = __builtin_amdgcn_mfma_f32_16x16x32_bf16(ah[a2], bl[b2], acc[a2][b2], 0, 0, 0);
                    acc[a2][b2] = __builtin_amdgcn_mfma_f32_16x16x32_bf16(al[a2], bh[b2], acc[a2][b2], 0, 0, 0);
                }
        }
    }

    // ---- epilogue: d2 = Pn + Qn - 2g, guarded sqrt, reduce ----
    const bool selfm = (type != 0) && (ti == tj);
    float lsum = 0.f;
    #pragma unroll
    for (int a2 = 0; a2 < 4; ++a2) {
        int ib = rowHalf + a2 * 16 + kq * 4;
        #pragma unroll
        for (int b2 = 0; b2 < 4; ++b2) {
            int j = colHalf + b2 * 16 + fm;
            float qn = Qn[j];
            #pragma unroll
            for (int rg = 0; rg < 4; ++rg) {
                int i = ib + rg;
                float d2 = Pn[i] + qn - 2.0f * acc[a2][b2][rg];
                if (d2 > 0.f && !(selfm && i == j)) lsum += sqrtf(d2);
            }
        }
    }
    #pragma unroll
    for (int off = 32; off > 0; off >>= 1) lsum += __shfl_down(lsum, off, 64);
    if (lane == 0) wred[wv] = lsum;
    __syncthreads();
    if (tid == 0)
        partials[bid] = (wred[0] + wred[1] + wred[2] + wred[3]) * w;
}

__global__ __launch_bounds__(256)
void mmd_finalize_kernel(const float* __restrict__ partials, int n,
                         float* __restrict__ out, double scale) {
    __shared__ double sh[256];
    double s = 0.0;
    for (int i = threadIdx.x; i < n; i += 256) s += (double)partials[i];
    sh[threadIdx.x] = s;
    __syncthreads();
    for (int off = 128; off > 0; off >>= 1) {
        if ((int)threadIdx.x < off) sh[threadIdx.x] += sh[threadIdx.x + off];
        __syncthreads();
    }
    if (threadIdx.x == 0) out[0] = (float)(sh[0] * scale);
}

extern "C" void kernel_launch(void* const* d_in, const int* in_sizes, int n_in,
                              void* d_out, int out_size, void* d_ws, size_t ws_size,
                              hipStream_t stream) {
    const float* x = (const float*)d_in[0];
    const float* y = (const float*)d_in[1];
    float* out = (float*)d_out;
    float* partials = (float*)d_ws;

    const int n = in_sizes[0];
    const int B = n / (DSAMP * DIM);       // 128
    const int nblocks = B * 48;            // 3 matrices x 16 tiles each

    mmd_tile_kernel<<<dim3(nblocks), dim3(256), 0, stream>>>(x, y, partials);
    mmd_finalize_kernel<<<dim3(1), dim3(256), 0, stream>>>(
        partials, nblocks, out, 1.0 / ((double)B * (double)DSAMP * (double)DSAMP));
}

// Round 2
// 238.610 us; speedup vs baseline: 1.2052x; 1.2052x over previous
//
#include <hip/hip_runtime.h>

typedef __attribute__((ext_vector_type(8))) __bf16 bf16x8;
typedef __attribute__((ext_vector_type(4))) float f32x4;
typedef __attribute__((ext_vector_type(8))) unsigned short ushort8;
typedef __attribute__((ext_vector_type(4))) unsigned short u16x4;

#define DSAMP 512
#define DIM   128
#define ROWB  144                    // LDS/global row pitch: 64 bf16 = 128 B + 16 B pad
#define S1    ((size_t)18874368)     // one hi or lo array: 128 b * 2 c * 512 r * 144 B
#define REGB  18432                  // one region per chunk: 128 rows * 144 B
#define WS_NEEDED ((size_t)(4 * S1 + 2 * 262144 + 6144 * 4))

// ---------------------------------------------------------------------------
// Pass 1: fp32 -> bf16 hi/lo Dekker split (RNE), chunk-major 144B-pitch layout,
// plus fp32 row norms. 8 rows/block, 32 lanes/row, 4 floats/lane.
// ---------------------------------------------------------------------------
__global__ __launch_bounds__(256)
void presplit_kernel(const float* __restrict__ x, const float* __restrict__ y,
                     char* __restrict__ ws) {
    const int tid = threadIdx.x;
    const int l   = tid & 31;                       // lane within row
    const int r   = blockIdx.x * 8 + (tid >> 5);    // 0..131071
    const int input = r >> 16;                      // 0=x, 1=y
    const int ri    = r & 65535;

    const float* src = (input ? y : x) + (size_t)ri * DIM + l * 4;
    float4 v = *(const float4*)src;
    float xs[4] = {v.x, v.y, v.z, v.w};

    u16x4 hv, lv;
    float s = 0.f;
    #pragma unroll
    for (int e = 0; e < 4; ++e) {
        float xv = xs[e];
        s += xv * xv;
        unsigned ub = __float_as_uint(xv);
        unsigned hr = (ub + 0x7fffu + ((ub >> 16) & 1u)) >> 16;
        float hf = __uint_as_float(hr << 16);
        float rs = xv - hf;                          // exact residual
        unsigned ul = __float_as_uint(rs);
        unsigned lr = (ul + 0x7fffu + ((ul >> 16) & 1u)) >> 16;
        hv[e] = (unsigned short)hr;
        lv[e] = (unsigned short)lr;
    }

    const int b  = ri >> 9;
    const int rb = ri & 511;
    const int c  = l >> 4;          // k-chunk 0/1
    const int col = (l & 15) * 4;   // element within 64-wide chunk
    char* hi = ws + (size_t)input * 2 * S1;
    char* lo = hi + S1;
    size_t off = ((size_t)(b * 2 + c) * 512 + rb) * ROWB + (size_t)col * 2;
    *(u16x4*)(hi + off) = hv;
    *(u16x4*)(lo + off) = lv;

    #pragma unroll
    for (int o = 16; o > 0; o >>= 1) s += __shfl_down(s, o, 32);
    if (l == 0) {
        float* nrm = (float*)(ws + 4 * S1) + (size_t)input * 65536;
        nrm[ri] = s;
    }
}

// ---------------------------------------------------------------------------
// Pass 2: 128x128 distance-matrix tile per block, bf16 hi/lo MFMA triple
// product, staging via async global_load_lds (width 16) from pre-split arrays.
// ---------------------------------------------------------------------------
__global__ __launch_bounds__(256, 2)
void mmd_tile_presplit(const char* __restrict__ ws, float* __restrict__ partials) {
    __shared__ __align__(16) char smem[4 * REGB];   // Ah, Al, Bh, Bl
    __shared__ float Pn[128];
    __shared__ float Qn[128];
    __shared__ float wred[4];

    char* Ah = smem;
    char* Al = smem + 1 * REGB;
    char* Bh = smem + 2 * REGB;
    char* Bl = smem + 3 * REGB;

    const int tid  = threadIdx.x;
    const int bid  = blockIdx.x;
    const int tj   = bid & 3;
    const int ti   = (bid >> 2) & 3;
    const int type = (bid >> 4) % 3;   // 0: xy, 1: xx, 2: yy
    const int b    = bid / 48;

    const char* Xhi = ws;
    const char* Yhi = ws + 2 * S1;
    const float* normX = (const float*)(ws + 4 * S1);
    const float* normY = normX + 65536;

    const char* Phi; const char* Qhi; const float* nP; const float* nQ; float w;
    if (type == 0)      { Phi = Xhi; Qhi = Yhi; nP = normX; nQ = normY; w = 1.0f;  }
    else if (type == 1) { Phi = Xhi; Qhi = Xhi; nP = normX; nQ = normX; w = -0.5f; }
    else                { Phi = Yhi; Qhi = Yhi; nP = normY; nQ = normY; w = -0.5f; }

    if (tid < 128) Pn[tid]       = nP[(size_t)b * 512 + ti * 128 + tid];
    else           Qn[tid - 128] = nQ[(size_t)b * 512 + tj * 128 + (tid - 128)];

    const int lane    = tid & 63;
    const int wv      = tid >> 6;
    const int rowHalf = (wv >> 1) * 64;
    const int colHalf = (wv & 1) * 64;
    const int fm      = lane & 15;
    const int kq      = lane >> 4;

    f32x4 acc[4][4];
    #pragma unroll
    for (int a2 = 0; a2 < 4; ++a2)
        #pragma unroll
        for (int b2 = 0; b2 < 4; ++b2)
            acc[a2][b2] = (f32x4){0.f, 0.f, 0.f, 0.f};

    for (int c = 0; c < 2; ++c) {
        if (c) __syncthreads();   // previous chunk's compute done before overwrite
        // async stage: wave wv copies region wv (0:P-hi 1:P-lo 2:Q-hi 3:Q-lo)
        {
            const char* gslice = ((wv & 2) ? Qhi : Phi)
                               + (size_t)(wv & 1) * S1
                               + ((size_t)(b * 2 + c) * 512 + ((wv & 2) ? tj : ti) * 128) * ROWB
                               + lane * 16;
            char* lb = smem + wv * REGB;
            #pragma unroll
            for (int sub = 0; sub < 18; ++sub) {
                __builtin_amdgcn_global_load_lds(
                    (const __attribute__((address_space(1))) void*)(gslice + sub * 1024),
                    (__attribute__((address_space(3))) void*)(lb + sub * 1024),
                    16, 0, 0);
            }
        }
        __syncthreads();
        #pragma unroll
        for (int ks = 0; ks < 2; ++ks) {
            const int kb2 = (ks * 32 + kq * 8) * 2;
            bf16x8 ah[4], al[4], bh[4], bl[4];
            #pragma unroll
            for (int a2 = 0; a2 < 4; ++a2) {
                int ar = rowHalf + a2 * 16 + fm;
                ah[a2] = *(const bf16x8*)(Ah + ar * ROWB + kb2);
                al[a2] = *(const bf16x8*)(Al + ar * ROWB + kb2);
            }
            #pragma unroll
            for (int b2 = 0; b2 < 4; ++b2) {
                int br = colHalf + b2 * 16 + fm;
                bh[b2] = *(const bf16x8*)(Bh + br * ROWB + kb2);
                bl[b2] = *(const bf16x8*)(Bl + br * ROWB + kb2);
            }
            #pragma unroll
            for (int a2 = 0; a2 < 4; ++a2)
                #pragma unroll
                for (int b2 = 0; b2 < 4; ++b2) {
                    acc[a2][b2] = __builtin_amdgcn_mfma_f32_16x16x32_bf16(ah[a2], bh[b2], acc[a2][b2], 0, 0, 0);
                    acc[a2][b2] = __builtin_amdgcn_mfma_f32_16x16x32_bf16(ah[a2], bl[b2], acc[a2][b2], 0, 0, 0);
                    acc[a2][b2] = __builtin_amdgcn_mfma_f32_16x16x32_bf16(al[a2], bh[b2], acc[a2][b2], 0, 0, 0);
                }
        }
    }

    const bool selfm = (type != 0) && (ti == tj);
    float lsum = 0.f;
    #pragma unroll
    for (int a2 = 0; a2 < 4; ++a2) {
        int ib = rowHalf + a2 * 16 + kq * 4;
        #pragma unroll
        for (int b2 = 0; b2 < 4; ++b2) {
            int j = colHalf + b2 * 16 + fm;
            float qn = Qn[j];
            #pragma unroll
            for (int rg = 0; rg < 4; ++rg) {
                int i = ib + rg;
                float d2 = Pn[i] + qn - 2.0f * acc[a2][b2][rg];
                if (d2 > 0.f && !(selfm && i == j)) lsum += sqrtf(d2);
            }
        }
    }
    #pragma unroll
    for (int off = 32; off > 0; off >>= 1) lsum += __shfl_down(lsum, off, 64);
    if (lane == 0) wred[wv] = lsum;
    __syncthreads();
    if (tid == 0)
        partials[bid] = (wred[0] + wred[1] + wred[2] + wred[3]) * w;
}

// ---------------------------------------------------------------------------
// Fallback (round-1 kernel, in-kernel conversion) if ws_size is too small.
// ---------------------------------------------------------------------------
__global__ __launch_bounds__(256, 2)
void mmd_tile_fallback(const float* __restrict__ x, const float* __restrict__ y,
                       float* __restrict__ partials) {
    __shared__ __align__(16) char smem[4 * 128 * ROWB];
    __shared__ float Pn[128];
    __shared__ float Qn[128];
    __shared__ float wred[4];

    char* Ah = smem;
    char* Al = smem + 1 * 128 * ROWB;
    char* Bh = smem + 2 * 128 * ROWB;
    char* Bl = smem + 3 * 128 * ROWB;

    const int tid  = threadIdx.x;
    const int bid  = blockIdx.x;
    const int tj   = bid & 3;
    const int ti   = (bid >> 2) & 3;
    const int type = (bid >> 4) % 3;
    const int b    = bid / 48;

    const float* Xb = x + (size_t)b * DSAMP * DIM;
    const float* Yb = y + (size_t)b * DSAMP * DIM;
    const float* Pp; const float* Qp; float w;
    if (type == 0)      { Pp = Xb; Qp = Yb; w = 1.0f;  }
    else if (type == 1) { Pp = Xb; Qp = Xb; w = -0.5f; }
    else                { Pp = Yb; Qp = Yb; w = -0.5f; }
    Pp += (size_t)ti * 128 * DIM;
    Qp += (size_t)tj * 128 * DIM;

    {
        const float* rp = (tid < 128) ? (Pp + (size_t)tid * DIM)
                                      : (Qp + (size_t)(tid - 128) * DIM);
        float s = 0.f;
        #pragma unroll
        for (int k4 = 0; k4 < 32; ++k4) {
            float4 v = ((const float4*)rp)[k4];
            s += v.x * v.x + v.y * v.y + v.z * v.z + v.w * v.w;
        }
        if (tid < 128) Pn[tid] = s; else Qn[tid - 128] = s;
    }

    const int lane    = tid & 63;
    const int wv      = tid >> 6;
    const int rowHalf = (wv >> 1) * 64;
    const int colHalf = (wv & 1) * 64;
    const int fm      = lane & 15;
    const int kq      = lane >> 4;

    f32x4 acc[4][4];
    #pragma unroll
    for (int a2 = 0; a2 < 4; ++a2)
        #pragma unroll
        for (int b2 = 0; b2 < 4; ++b2)
            acc[a2][b2] = (f32x4){0.f, 0.f, 0.f, 0.f};

    for (int c = 0; c < 2; ++c) {
        if (c) __syncthreads();
        #pragma unroll
        for (int side = 0; side < 2; ++side) {
            const float* sp = side ? Qp : Pp;
            char* dh = side ? Bh : Ah;
            char* dl = side ? Bl : Al;
            #pragma unroll
            for (int it = 0; it < 4; ++it) {
                int u  = it * 256 + tid;
                int r  = u >> 3;
                int c8 = u & 7;
                const float* g = sp + (size_t)r * DIM + c * 64 + c8 * 8;
                float4 v0 = ((const float4*)g)[0];
                float4 v1 = ((const float4*)g)[1];
                float xs[8] = {v0.x, v0.y, v0.z, v0.w, v1.x, v1.y, v1.z, v1.w};
                ushort8 hv, lv;
                #pragma unroll
                for (int e = 0; e < 8; ++e) {
                    float xv = xs[e];
                    unsigned ub = __float_as_uint(xv);
                    unsigned hr = (ub + 0x7fffu + ((ub >> 16) & 1u)) >> 16;
                    float hf = __uint_as_float(hr << 16);
                    float rs = xv - hf;
                    unsigned ul = __float_as_uint(rs);
                    unsigned lr = (ul + 0x7fffu + ((ul >> 16) & 1u)) >> 16;
                    hv[e] = (unsigned short)hr;
                    lv[e] = (unsigned short)lr;
                }
                *(ushort8*)(dh + r * ROWB + c8 * 16) = hv;
                *(ushort8*)(dl + r * ROWB + c8 * 16) = lv;
            }
        }
        __syncthreads();
        #pragma unroll
        for (int ks = 0; ks < 2; ++ks) {
            const int kb2 = (ks * 32 + kq * 8) * 2;
            bf16x8 ah[4], al[4], bh[4], bl[4];
            #pragma unroll
            for (int a2 = 0; a2 < 4; ++a2) {
                int ar = rowHalf + a2 * 16 + fm;
                ah[a2] = *(const bf16x8*)(Ah + ar * ROWB + kb2);
                al[a2] = *(const bf16x8*)(Al + ar * ROWB + kb2);
            }
            #pragma unroll
            for (int b2 = 0; b2 < 4; ++b2) {
                int br = colHalf + b2 * 16 + fm;
                bh[b2] = *(const bf16x8*)(Bh + br * ROWB + kb2);
                bl[b2] = *(const bf16x8*)(Bl + br * ROWB + kb2);
            }
            #pragma unroll
            for (int a2 = 0; a2 < 4; ++a2)
                #pragma unroll
                for (int b2 = 0; b2 < 4; ++b2) {
                    acc[a2][b2] = __builtin_amdgcn_mfma_f32_16x16x32_bf16(ah[a2], bh[b2], acc[a2][b2], 0, 0, 0);
                    acc[a2][b2] = __builtin_amdgcn_mfma_f32_16x16x32_bf16(ah[a2], bl[b2], acc[a2][b2], 0, 0, 0);
                    acc[a2][b2] = __builtin_amdgcn_mfma_f32_16x16x32_bf16(al[a2], bh[b2], acc[a2][b2], 0, 0, 0);
                }
        }
    }

    const bool selfm = (type != 0) && (ti == tj);
    float lsum = 0.f;
    #pragma unroll
    for (int a2 = 0; a2 < 4; ++a2) {
        int ib = rowHalf + a2 * 16 + kq * 4;
        #pragma unroll
        for (int b2 = 0; b2 < 4; ++b2) {
            int j = colHalf + b2 * 16 + fm;
            float qn = Qn[j];
            #pragma unroll
            for (int rg = 0; rg < 4; ++rg) {
                int i = ib + rg;
                float d2 = Pn[i] + qn - 2.0f * acc[a2][b2][rg];
                if (d2 > 0.f && !(selfm && i == j)) lsum += sqrtf(d2);
            }
        }
    }
    #pragma unroll
    for (int off = 32; off > 0; off >>= 1) lsum += __shfl_down(lsum, off, 64);
    if (lane == 0) wred[wv] = lsum;
    __syncthreads();
    if (tid == 0)
        partials[bid] = (wred[0] + wred[1] + wred[2] + wred[3]) * w;
}

__global__ __launch_bounds__(256)
void mmd_finalize_kernel(const float* __restrict__ partials, int n,
                         float* __restrict__ out, double scale) {
    __shared__ double sh[256];
    double s = 0.0;
    for (int i = threadIdx.x; i < n; i += 256) s += (double)partials[i];
    sh[threadIdx.x] = s;
    __syncthreads();
    for (int off = 128; off > 0; off >>= 1) {
        if ((int)threadIdx.x < off) sh[threadIdx.x] += sh[threadIdx.x + off];
        __syncthreads();
    }
    if (threadIdx.x == 0) out[0] = (float)(sh[0] * scale);
}

extern "C" void kernel_launch(void* const* d_in, const int* in_sizes, int n_in,
                              void* d_out, int out_size, void* d_ws, size_t ws_size,
                              hipStream_t stream) {
    const float* x = (const float*)d_in[0];
    const float* y = (const float*)d_in[1];
    float* out = (float*)d_out;

    const int n = in_sizes[0];
    const int B = n / (DSAMP * DIM);       // 128
    const int nblocks = B * 48;            // 3 matrices x 16 tiles each
    const double scale = 1.0 / ((double)B * (double)DSAMP * (double)DSAMP);

    if (ws_size >= WS_NEEDED) {
        char* ws = (char*)d_ws;
        float* partials = (float*)(ws + 4 * S1 + 2 * 262144);
        presplit_kernel<<<dim3(16384), dim3(256), 0, stream>>>(x, y, ws);
        mmd_tile_presplit<<<dim3(nblocks), dim3(256), 0, stream>>>(ws, partials);
        mmd_finalize_kernel<<<dim3(1), dim3(256), 0, stream>>>(partials, nblocks, out, scale);
    } else {
        float* partials = (float*)d_ws;
        mmd_tile_fallback<<<dim3(nblocks), dim3(256), 0, stream>>>(x, y, partials);
        mmd_finalize_kernel<<<dim3(1), dim3(256), 0, stream>>>(partials, nblocks, out, scale);
    }
}

// Round 3
// 187.405 us; speedup vs baseline: 1.5344x; 1.2732x over previous
//
#include <hip/hip_runtime.h>

typedef __attribute__((ext_vector_type(8))) __bf16 bf16x8;
typedef __attribute__((ext_vector_type(4))) float f32x4;
typedef __attribute__((ext_vector_type(8))) unsigned short ushort8;
typedef __attribute__((ext_vector_type(4))) unsigned short u16x4;

#define DSAMP 512
#define DIM   128
#define ROWB  144                    // padded row pitch: 64 bf16 = 128 B + 16 B
#define S1    ((size_t)18874368)     // one hi or lo array: 128 b * 2 c * 512 r * 144 B
#define REGB  18432                  // one staged region: 128 rows * 144 B
#define WS_NEEDED ((size_t)(4 * S1 + 2 * 262144 + 6144 * 4))

// ---------------------------------------------------------------------------
// Pass 1 v2: coalesced flat loads -> register split -> padded LDS images ->
// linear (fully coalesced) b128 copy-out. Block = 64 rows of one input.
// ---------------------------------------------------------------------------
__global__ __launch_bounds__(256)
void presplit2(const float* __restrict__ x, const float* __restrict__ y,
               char* __restrict__ ws) {
    __shared__ __align__(16) char img[4 * 9216];   // [hl*2+chunk]: 64 rows x 144 B
    __shared__ float nrm[64];

    const int tid = threadIdx.x;
    const int nb  = gridDim.x >> 1;
    const int input = (blockIdx.x >= nb) ? 1 : 0;
    const int rb    = blockIdx.x - input * nb;      // 64-row group index

    const float* src = (input ? y : x) + (size_t)rb * 64 * DIM;

    #pragma unroll
    for (int i = 0; i < 8; ++i) {
        int f  = i * 256 + tid;        // flat float4 index, 0..2047 (coalesced)
        int r  = f >> 5;               // row 0..63 (32 float4 per row)
        int k4 = f & 31;               // float4 within row; k = k4*4
        float4 v = ((const float4*)src)[f];

        // row norm: each row spans exactly one aligned 32-lane group
        float s = v.x * v.x + v.y * v.y + v.z * v.z + v.w * v.w;
        #pragma unroll
        for (int o = 16; o > 0; o >>= 1) s += __shfl_down(s, o, 32);
        if ((tid & 31) == 0) nrm[r] = s;

        float xs[4] = {v.x, v.y, v.z, v.w};
        u16x4 hv, lv;
        #pragma unroll
        for (int e = 0; e < 4; ++e) {
            float xv = xs[e];
            unsigned ub = __float_as_uint(xv);
            unsigned hr = (ub + 0x7fffu + ((ub >> 16) & 1u)) >> 16;
            float hf = __uint_as_float(hr << 16);
            float rs = xv - hf;                      // exact residual (Dekker)
            unsigned ul = __float_as_uint(rs);
            unsigned lr = (ul + 0x7fffu + ((ul >> 16) & 1u)) >> 16;
            hv[e] = (unsigned short)hr;
            lv[e] = (unsigned short)lr;
        }
        int c    = k4 >> 4;            // k-chunk 0/1
        int col8 = (k4 & 15) * 8;      // byte offset within 64-wide chunk row
        *(u16x4*)(img + (size_t)(0 + c) * 9216 + r * ROWB + col8) = hv;
        *(u16x4*)(img + (size_t)(2 + c) * 9216 + r * ROWB + col8) = lv;
    }
    __syncthreads();

    // copy-out: wave wv owns image wv (hl = wv>>1, chunk = wv&1), linear b128
    const int wv = tid >> 6, lane = tid & 63;
    const int hl = wv >> 1, ch = wv & 1;
    const int b     = rb >> 3;           // batch
    const int rowin = (rb & 7) * 64;     // first row within batch
    char* gdst = ws + (size_t)input * 2 * S1 + (size_t)hl * S1
               + ((size_t)(b * 2 + ch) * 512 + rowin) * ROWB;
    const char* lsrc = img + (size_t)wv * 9216;
    #pragma unroll
    for (int j = 0; j < 9; ++j) {
        int o = (j * 64 + lane) * 16;    // 0..9215
        *(float4*)(gdst + o) = *(const float4*)(lsrc + o);
    }
    if (tid < 64) {
        float* nG = (float*)(ws + 4 * S1) + (size_t)input * 65536 + rb * 64;
        nG[tid] = nrm[tid];
    }
}

// ---------------------------------------------------------------------------
// Pass 2: 128x128 tile, TWO-term product (hh + hi*lo), async staging of
// 3 regions (Ah, Bh, Bl), register-cached cheap epilogue.
// ---------------------------------------------------------------------------
__global__ __launch_bounds__(256, 2)
void mmd_tile3(const char* __restrict__ ws, float* __restrict__ partials) {
    __shared__ __align__(16) char smem[3 * REGB];   // Ah, Bh, Bl
    __shared__ float Pn[128];
    __shared__ float Qn[128];
    __shared__ float wred[4];

    char* Ah = smem;
    char* Bh = smem + 1 * REGB;
    char* Bl = smem + 2 * REGB;

    const int tid  = threadIdx.x;
    const int bid  = blockIdx.x;
    const int tj   = bid & 3;
    const int ti   = (bid >> 2) & 3;
    const int type = (bid >> 4) % 3;   // 0: xy, 1: xx, 2: yy
    const int b    = bid / 48;

    const char* Xhi = ws;
    const char* Yhi = ws + 2 * S1;
    const float* normX = (const float*)(ws + 4 * S1);
    const float* normY = normX + 65536;

    const char* Phi; const char* Qhi; const float* nP; const float* nQ; float w;
    if (type == 0)      { Phi = Xhi; Qhi = Yhi; nP = normX; nQ = normY; w = 1.0f;  }
    else if (type == 1) { Phi = Xhi; Qhi = Xhi; nP = normX; nQ = normX; w = -0.5f; }
    else                { Phi = Yhi; Qhi = Yhi; nP = normY; nQ = normY; w = -0.5f; }

    if (tid < 128) Pn[tid]       = nP[(size_t)b * 512 + ti * 128 + tid];
    else           Qn[tid - 128] = nQ[(size_t)b * 512 + tj * 128 + (tid - 128)];

    const int lane    = tid & 63;
    const int wv      = tid >> 6;
    const int rowHalf = (wv >> 1) * 64;
    const int colHalf = (wv & 1) * 64;
    const int fm      = lane & 15;
    const int kq      = lane >> 4;

    f32x4 acc[4][4];
    #pragma unroll
    for (int a2 = 0; a2 < 4; ++a2)
        #pragma unroll
        for (int b2 = 0; b2 < 4; ++b2)
            acc[a2][b2] = (f32x4){0.f, 0.f, 0.f, 0.f};

    for (int c = 0; c < 2; ++c) {
        if (c) __syncthreads();
        // waves 0,1,2 stage Ah (P hi), Bh (Q hi), Bl (Q lo); wave 3 idles
        if (wv < 3) {
            size_t roff = ((size_t)(b * 2 + c) * 512 + (wv ? tj : ti) * 128) * ROWB
                        + (size_t)lane * 16;
            const char* gs;
            if (wv == 0)      gs = Phi + roff;
            else if (wv == 1) gs = Qhi + roff;
            else              gs = Qhi + S1 + roff;
            char* lb = smem + (size_t)wv * REGB;
            #pragma unroll
            for (int sub = 0; sub < 18; ++sub) {
                __builtin_amdgcn_global_load_lds(
                    (const __attribute__((address_space(1))) void*)(gs + sub * 1024),
                    (__attribute__((address_space(3))) void*)(lb + sub * 1024),
                    16, 0, 0);
            }
        }
        __syncthreads();
        #pragma unroll
        for (int ks = 0; ks < 2; ++ks) {
            const int kb2 = (ks * 32 + kq * 8) * 2;
            bf16x8 ah[4], bh[4], bl[4];
            #pragma unroll
            for (int a2 = 0; a2 < 4; ++a2) {
                int ar = rowHalf + a2 * 16 + fm;
                ah[a2] = *(const bf16x8*)(Ah + ar * ROWB + kb2);
            }
            #pragma unroll
            for (int b2 = 0; b2 < 4; ++b2) {
                int br = colHalf + b2 * 16 + fm;
                bh[b2] = *(const bf16x8*)(Bh + br * ROWB + kb2);
                bl[b2] = *(const bf16x8*)(Bl + br * ROWB + kb2);
            }
            #pragma unroll
            for (int a2 = 0; a2 < 4; ++a2)
                #pragma unroll
                for (int b2 = 0; b2 < 4; ++b2) {
                    acc[a2][b2] = __builtin_amdgcn_mfma_f32_16x16x32_bf16(ah[a2], bh[b2], acc[a2][b2], 0, 0, 0);
                    acc[a2][b2] = __builtin_amdgcn_mfma_f32_16x16x32_bf16(ah[a2], bl[b2], acc[a2][b2], 0, 0, 0);
                }
        }
    }

    // ---- epilogue: register-cached norms, fma+max+hw-sqrt ----
    const bool selfm = (type != 0) && (ti == tj);
    float Pr[16], Qc[4];
    #pragma unroll
    for (int a2 = 0; a2 < 4; ++a2)
        #pragma unroll
        for (int rg = 0; rg < 4; ++rg)
            Pr[a2 * 4 + rg] = Pn[rowHalf + a2 * 16 + kq * 4 + rg];
    #pragma unroll
    for (int b2 = 0; b2 < 4; ++b2) Qc[b2] = Qn[colHalf + b2 * 16 + fm];

    float lsum = 0.f;
    #pragma unroll
    for (int a2 = 0; a2 < 4; ++a2) {
        #pragma unroll
        for (int b2 = 0; b2 < 4; ++b2) {
            #pragma unroll
            for (int rg = 0; rg < 4; ++rg) {
                float d2 = fmaf(-2.0f, acc[a2][b2][rg], Pr[a2 * 4 + rg] + Qc[b2]);
                float r  = __builtin_amdgcn_sqrtf(fmaxf(d2, 0.0f));
                if (selfm && (rowHalf + a2 * 16 + kq * 4 + rg) == (colHalf + b2 * 16 + fm))
                    r = 0.0f;
                lsum += r;
            }
        }
    }
    #pragma unroll
    for (int off = 32; off > 0; off >>= 1) lsum += __shfl_down(lsum, off, 64);
    if (lane == 0) wred[wv] = lsum;
    __syncthreads();
    if (tid == 0)
        partials[bid] = (wred[0] + wred[1] + wred[2] + wred[3]) * w;
}

// ---------------------------------------------------------------------------
// Fallback (round-1 kernel, in-kernel conversion) if ws_size is too small.
// ---------------------------------------------------------------------------
__global__ __launch_bounds__(256, 2)
void mmd_tile_fallback(const float* __restrict__ x, const float* __restrict__ y,
                       float* __restrict__ partials) {
    __shared__ __align__(16) char smem[4 * 128 * ROWB];
    __shared__ float Pn[128];
    __shared__ float Qn[128];
    __shared__ float wred[4];

    char* Ah = smem;
    char* Al = smem + 1 * 128 * ROWB;
    char* Bh = smem + 2 * 128 * ROWB;
    char* Bl = smem + 3 * 128 * ROWB;

    const int tid  = threadIdx.x;
    const int bid  = blockIdx.x;
    const int tj   = bid & 3;
    const int ti   = (bid >> 2) & 3;
    const int type = (bid >> 4) % 3;
    const int b    = bid / 48;

    const float* Xb = x + (size_t)b * DSAMP * DIM;
    const float* Yb = y + (size_t)b * DSAMP * DIM;
    const float* Pp; const float* Qp; float w;
    if (type == 0)      { Pp = Xb; Qp = Yb; w = 1.0f;  }
    else if (type == 1) { Pp = Xb; Qp = Xb; w = -0.5f; }
    else                { Pp = Yb; Qp = Yb; w = -0.5f; }
    Pp += (size_t)ti * 128 * DIM;
    Qp += (size_t)tj * 128 * DIM;

    {
        const float* rp = (tid < 128) ? (Pp + (size_t)tid * DIM)
                                      : (Qp + (size_t)(tid - 128) * DIM);
        float s = 0.f;
        #pragma unroll
        for (int k4 = 0; k4 < 32; ++k4) {
            float4 v = ((const float4*)rp)[k4];
            s += v.x * v.x + v.y * v.y + v.z * v.z + v.w * v.w;
        }
        if (tid < 128) Pn[tid] = s; else Qn[tid - 128] = s;
    }

    const int lane    = tid & 63;
    const int wv      = tid >> 6;
    const int rowHalf = (wv >> 1) * 64;
    const int colHalf = (wv & 1) * 64;
    const int fm      = lane & 15;
    const int kq      = lane >> 4;

    f32x4 acc[4][4];
    #pragma unroll
    for (int a2 = 0; a2 < 4; ++a2)
        #pragma unroll
        for (int b2 = 0; b2 < 4; ++b2)
            acc[a2][b2] = (f32x4){0.f, 0.f, 0.f, 0.f};

    for (int c = 0; c < 2; ++c) {
        if (c) __syncthreads();
        #pragma unroll
        for (int side = 0; side < 2; ++side) {
            const float* sp = side ? Qp : Pp;
            char* dh = side ? Bh : Ah;
            char* dl = side ? Bl : Al;
            #pragma unroll
            for (int it = 0; it < 4; ++it) {
                int u  = it * 256 + tid;
                int r  = u >> 3;
                int c8 = u & 7;
                const float* g = sp + (size_t)r * DIM + c * 64 + c8 * 8;
                float4 v0 = ((const float4*)g)[0];
                float4 v1 = ((const float4*)g)[1];
                float xs[8] = {v0.x, v0.y, v0.z, v0.w, v1.x, v1.y, v1.z, v1.w};
                ushort8 hv, lv;
                #pragma unroll
                for (int e = 0; e < 8; ++e) {
                    float xv = xs[e];
                    unsigned ub = __float_as_uint(xv);
                    unsigned hr = (ub + 0x7fffu + ((ub >> 16) & 1u)) >> 16;
                    float hf = __uint_as_float(hr << 16);
                    float rs = xv - hf;
                    unsigned ul = __float_as_uint(rs);
                    unsigned lr = (ul + 0x7fffu + ((ul >> 16) & 1u)) >> 16;
                    hv[e] = (unsigned short)hr;
                    lv[e] = (unsigned short)lr;
                }
                *(ushort8*)(dh + r * ROWB + c8 * 16) = hv;
                *(ushort8*)(dl + r * ROWB + c8 * 16) = lv;
            }
        }
        __syncthreads();
        #pragma unroll
        for (int ks = 0; ks < 2; ++ks) {
            const int kb2 = (ks * 32 + kq * 8) * 2;
            bf16x8 ah[4], al[4], bh[4], bl[4];
            #pragma unroll
            for (int a2 = 0; a2 < 4; ++a2) {
                int ar = rowHalf + a2 * 16 + fm;
                ah[a2] = *(const bf16x8*)(Ah + ar * ROWB + kb2);
                al[a2] = *(const bf16x8*)(Al + ar * ROWB + kb2);
            }
            #pragma unroll
            for (int b2 = 0; b2 < 4; ++b2) {
                int br = colHalf + b2 * 16 + fm;
                bh[b2] = *(const bf16x8*)(Bh + br * ROWB + kb2);
                bl[b2] = *(const bf16x8*)(Bl + br * ROWB + kb2);
            }
            #pragma unroll
            for (int a2 = 0; a2 < 4; ++a2)
                #pragma unroll
                for (int b2 = 0; b2 < 4; ++b2) {
                    acc[a2][b2] = __builtin_amdgcn_mfma_f32_16x16x32_bf16(ah[a2], bh[b2], acc[a2][b2], 0, 0, 0);
                    acc[a2][b2] = __builtin_amdgcn_mfma_f32_16x16x32_bf16(ah[a2], bl[b2], acc[a2][b2], 0, 0, 0);
                    acc[a2][b2] = __builtin_amdgcn_mfma_f32_16x16x32_bf16(al[a2], bh[b2], acc[a2][b2], 0, 0, 0);
                }
        }
    }

    const bool selfm = (type != 0) && (ti == tj);
    float lsum = 0.f;
    #pragma unroll
    for (int a2 = 0; a2 < 4; ++a2) {
        int ib = rowHalf + a2 * 16 + kq * 4;
        #pragma unroll
        for (int b2 = 0; b2 < 4; ++b2) {
            int j = colHalf + b2 * 16 + fm;
            float qn = Qn[j];
            #pragma unroll
            for (int rg = 0; rg < 4; ++rg) {
                int i = ib + rg;
                float d2 = Pn[i] + qn - 2.0f * acc[a2][b2][rg];
                if (d2 > 0.f && !(selfm && i == j)) lsum += sqrtf(d2);
            }
        }
    }
    #pragma unroll
    for (int off = 32; off > 0; off >>= 1) lsum += __shfl_down(lsum, off, 64);
    if (lane == 0) wred[wv] = lsum;
    __syncthreads();
    if (tid == 0)
        partials[bid] = (wred[0] + wred[1] + wred[2] + wred[3]) * w;
}

__global__ __launch_bounds__(256)
void mmd_finalize_kernel(const float* __restrict__ partials, int n,
                         float* __restrict__ out, double scale) {
    __shared__ double sh[256];
    double s = 0.0;
    for (int i = threadIdx.x; i < n; i += 256) s += (double)partials[i];
    sh[threadIdx.x] = s;
    __syncthreads();
    for (int off = 128; off > 0; off >>= 1) {
        if ((int)threadIdx.x < off) sh[threadIdx.x] += sh[threadIdx.x + off];
        __syncthreads();
    }
    if (threadIdx.x == 0) out[0] = (float)(sh[0] * scale);
}

extern "C" void kernel_launch(void* const* d_in, const int* in_sizes, int n_in,
                              void* d_out, int out_size, void* d_ws, size_t ws_size,
                              hipStream_t stream) {
    const float* x = (const float*)d_in[0];
    const float* y = (const float*)d_in[1];
    float* out = (float*)d_out;

    const int n = in_sizes[0];
    const int B = n / (DSAMP * DIM);       // 128
    const int nblocks = B * 48;
    const double scale = 1.0 / ((double)B * (double)DSAMP * (double)DSAMP);

    if (ws_size >= WS_NEEDED) {
        char* ws = (char*)d_ws;
        float* partials = (float*)(ws + 4 * S1 + 2 * 262144);
        const int nb = (n / DIM) / 64;     // 1024: 64-row groups per input
        presplit2<<<dim3(2 * nb), dim3(256), 0, stream>>>(x, y, ws);
        mmd_tile3<<<dim3(nblocks), dim3(256), 0, stream>>>(ws, partials);
        mmd_finalize_kernel<<<dim3(1), dim3(256), 0, stream>>>(partials, nblocks, out, scale);
    } else {
        float* partials = (float*)d_ws;
        mmd_tile_fallback<<<dim3(nblocks), dim3(256), 0, stream>>>(x, y, partials);
        mmd_finalize_kernel<<<dim3(1), dim3(256), 0, stream>>>(partials, nblocks, out, scale);
    }
}